// Round 5
// baseline (316.773 us; speedup 1.0000x reference)
//
#include <hip/hip_runtime.h>
#include <cmath>

// Problem constants: B=32768, N=17, D=2, K=3, H=64
#define NBATCH 32768
#define NJOINT 17
#define OUT0_ELEMS (NBATCH * NJOINT * 15)          // out[B,N,3,5]
#define KJS_OFF    OUT0_ELEMS                      // k_js[B,N]
#define MASK_OFF   (KJS_OFF + NBATCH * NJOINT)     // mask[B,N,3]

// fp64 weight workspace layout (per joint n, stride 774 doubles):
//  [0,128)   kW1  ([2][64]: row0=+0, row1=+64)
//  [128,192) kb1
//  [192,384) kW2  ([64][3])
//  [384,387) kb2
//  +387      same for the w-MLP
#define WN_STRIDE 774
#define WS_DOUBLES (NJOINT * WN_STRIDE)

__device__ __forceinline__ float sel3f(int i, float a, float b, float c) {
    return (i == 0) ? a : ((i == 1) ? b : c);
}

// --------------------------------------------------------------------------
// Prelude: convert k/w weights to fp64 once per launch.
// --------------------------------------------------------------------------
__global__ void cvt_weights_f64(
    const float* __restrict__ kW1, const float* __restrict__ kb1,
    const float* __restrict__ kW2, const float* __restrict__ kb2,
    const float* __restrict__ wW1, const float* __restrict__ wb1,
    const float* __restrict__ wW2, const float* __restrict__ wb2,
    double* __restrict__ dws)
{
    const int n = blockIdx.x;
    double* o = dws + (size_t)n * WN_STRIDE;
    for (int i = threadIdx.x; i < WN_STRIDE; i += blockDim.x) {
        int j = i;
        const float* W1 = kW1; const float* b1 = kb1;
        const float* W2 = kW2; const float* b2 = kb2;
        if (j >= 387) { j -= 387; W1 = wW1; b1 = wb1; W2 = wW2; b2 = wb2; }
        float v;
        if (j < 128)      v = W1[n * 128 + j];
        else if (j < 192) v = b1[n * 64 + (j - 128)];
        else if (j < 384) v = W2[n * 192 + (j - 192)];
        else              v = b2[n * 3 + (j - 384)];
        o[i] = (double)v;
    }
}

// --------------------------------------------------------------------------
// Per-point compute; math bit-identical to the passing kernels.
// USE_WS path: weight pointers are offset by an OPAQUE zero VGPR so the
// compiler cannot prove uniformity -> emits VECTOR (global_load) streams
// with deep VMEM pipelining instead of chunk-serialized s_load/waitcnt.
// All lanes read the same address: one cache line per wave, L1-resident.
// --------------------------------------------------------------------------
template<bool USE_WS>
__device__ __forceinline__ void compute_point(
    int n, float x0f, float x1f,
    const float* __restrict__ kW1, const float* __restrict__ kb1,
    const float* __restrict__ kW2, const float* __restrict__ kb2,
    const float* __restrict__ wW1, const float* __restrict__ wb1,
    const float* __restrict__ wW2, const float* __restrict__ wb2,
    const float* __restrict__ bW1, const float* __restrict__ bb1,
    const float* __restrict__ bW2, const float* __restrict__ bb2,
    const double* __restrict__ dws,
    float r[15], int& kj_out)
{
    const double x0 = (double)x0f, x1 = (double)x1f;
    double kl0, kl1, kl2, wl0, wl1, wl2;

    int vz;                                  // opaque 0 (VGPR) — defeats
    asm volatile("v_mov_b32 %0, 0" : "=v"(vz));  // uniformity analysis

    if constexpr (USE_WS) {
        const double* Wn = dws + (size_t)n * WN_STRIDE + vz;
        {   // kMLP (fp64) — vector-loaded weight stream
            const double* W1a = Wn;
            const double* W1b = Wn + 64;
            const double* b1  = Wn + 128;
            const double* W2  = Wn + 192;
            kl0 = Wn[384]; kl1 = Wn[385]; kl2 = Wn[386];
            #pragma unroll 4
            for (int h = 0; h < 64; ++h) {
                double hv = fmax(fma(x1, W1b[h], fma(x0, W1a[h], b1[h])), 0.0);
                kl0 = fma(hv, W2[h * 3 + 0], kl0);
                kl1 = fma(hv, W2[h * 3 + 1], kl1);
                kl2 = fma(hv, W2[h * 3 + 2], kl2);
            }
        }
        {   // wMLP (fp64)
            const double* W1a = Wn + 387;
            const double* W1b = Wn + 451;
            const double* b1  = Wn + 515;
            const double* W2  = Wn + 579;
            wl0 = Wn[771]; wl1 = Wn[772]; wl2 = Wn[773];
            #pragma unroll 4
            for (int h = 0; h < 64; ++h) {
                double hv = fmax(fma(x1, W1b[h], fma(x0, W1a[h], b1[h])), 0.0);
                wl0 = fma(hv, W2[h * 3 + 0], wl0);
                wl1 = fma(hv, W2[h * 3 + 1], wl1);
                wl2 = fma(hv, W2[h * 3 + 2], wl2);
            }
        }
    } else {
        {   // kMLP fallback: fp32 + in-loop cvt (identical to first passing kernel)
            const float* W1a = kW1 + n * 128;
            const float* W1b = W1a + 64;
            const float* b1  = kb1 + n * 64;
            const float* W2  = kW2 + n * 192;
            kl0 = (double)kb2[n * 3 + 0];
            kl1 = (double)kb2[n * 3 + 1];
            kl2 = (double)kb2[n * 3 + 2];
            #pragma unroll 4
            for (int h = 0; h < 64; ++h) {
                double hv = fma(x1, (double)W1b[h], fma(x0, (double)W1a[h], (double)b1[h]));
                hv = fmax(hv, 0.0);
                kl0 = fma(hv, (double)W2[h * 3 + 0], kl0);
                kl1 = fma(hv, (double)W2[h * 3 + 1], kl1);
                kl2 = fma(hv, (double)W2[h * 3 + 2], kl2);
            }
        }
        {   // wMLP fallback
            const float* W1a = wW1 + n * 128;
            const float* W1b = W1a + 64;
            const float* b1  = wb1 + n * 64;
            const float* W2  = wW2 + n * 192;
            wl0 = (double)wb2[n * 3 + 0];
            wl1 = (double)wb2[n * 3 + 1];
            wl2 = (double)wb2[n * 3 + 2];
            #pragma unroll 4
            for (int h = 0; h < 64; ++h) {
                double hv = fma(x1, (double)W1b[h], fma(x0, (double)W1a[h], (double)b1[h]));
                hv = fmax(hv, 0.0);
                wl0 = fma(hv, (double)W2[h * 3 + 0], wl0);
                wl1 = fma(hv, (double)W2[h * 3 + 1], wl1);
                wl2 = fma(hv, (double)W2[h * 3 + 2], wl2);
            }
        }
    }

    // argmax (first-occurrence, jnp.argmax semantics)
    int kj = 0;
    {
        double m = kl0;
        if (kl1 > m) { m = kl1; kj = 1; }
        if (kl2 > m) { kj = 2; }
    }
    kj_out = kj;

    // stable descending argsort of 3 (jnp.argsort(-w))
    int i0 = 0;
    {
        double m = wl0;
        if (wl1 > m) { m = wl1; i0 = 1; }
        if (wl2 > m) { i0 = 2; }
    }
    const int ia = (i0 == 0) ? 1 : 0;
    const int ib = (i0 == 2) ? 1 : 2;
    const double wa = ia ? wl1 : wl0;
    const double wb = (ib == 1) ? wl1 : wl2;
    const int i1 = (wb > wa) ? ib : ia;
    const int i2 = (wb > wa) ? ia : ib;

    // softmax weights (original order into out[...,0])
    const double mw = fmax(fmax(wl0, wl1), wl2);
    const float e0 = __expf((float)(wl0 - mw));
    const float e1 = __expf((float)(wl1 - mw));
    const float e2 = __expf((float)(wl2 - mw));
    const float inv = 1.0f / (e0 + e1 + e2);
    const float p0 = e0 * inv, p1 = e1 * inv, p2 = e2 * inv;

    // bMLP (fp32): 2 -> 128 -> 12 — vector-loaded weight stream
    float acc[12];
    {
        const float* W1a = bW1 + n * 256 + vz;
        const float* W1b = W1a + 128;
        const float* b1  = bb1 + n * 128 + vz;
        const float* W2  = bW2 + n * 1536 + vz;
        const float* b2  = bb2 + n * 12;           // tiny: leave scalar
        #pragma unroll
        for (int j = 0; j < 12; ++j) acc[j] = b2[j];
        #pragma unroll 4
        for (int h = 0; h < 128; ++h) {
            float hv = fmaxf(fmaf(x1f, W1b[h], fmaf(x0f, W1a[h], b1[h])), 0.0f);
            #pragma unroll
            for (int j = 0; j < 12; ++j)
                acc[j] = fmaf(hv, W2[h * 12 + j], acc[j]);
        }
    }

    // epilogue: gather by sort order
    r[0]  = p0; r[5] = p1; r[10] = p2;
    r[1]  = sel3f(i0, acc[0], acc[4], acc[8]);
    r[2]  = sel3f(i0, acc[1], acc[5], acc[9]);
    r[3]  = __expf(sel3f(i0, acc[2], acc[6], acc[10]));
    r[4]  = __expf(sel3f(i0, acc[3], acc[7], acc[11]));
    r[6]  = sel3f(i1, acc[0], acc[4], acc[8]);
    r[7]  = sel3f(i1, acc[1], acc[5], acc[9]);
    r[8]  = __expf(sel3f(i1, acc[2], acc[6], acc[10]));
    r[9]  = __expf(sel3f(i1, acc[3], acc[7], acc[11]));
    r[11] = sel3f(i2, acc[0], acc[4], acc[8]);
    r[12] = sel3f(i2, acc[1], acc[5], acc[9]);
    r[13] = __expf(sel3f(i2, acc[2], acc[6], acc[10]));
    r[14] = __expf(sel3f(i2, acc[3], acc[7], acc[11]));
}

// --------------------------------------------------------------------------
// Block = 4 waves; wave w handles n = 4*blockIdx.y + w; lane handles
// b = blockIdx.x*64 + lane. Output tile (64 b x 4 n) staged in LDS
// (stride-17 slots), written back as contiguous 240B-per-b runs.
// Structure identical to the 70 µs round-1 kernel; only the weight-load
// pipe changed (scalar -> vector).
// --------------------------------------------------------------------------
template<bool USE_WS>
__global__ __launch_bounds__(256, 2) void mdn_fused(
    const float* __restrict__ pred_pts,
    const float* __restrict__ kW1, const float* __restrict__ kb1,
    const float* __restrict__ kW2, const float* __restrict__ kb2,
    const float* __restrict__ wW1, const float* __restrict__ wb1,
    const float* __restrict__ wW2, const float* __restrict__ wb2,
    const float* __restrict__ bW1, const float* __restrict__ bb1,
    const float* __restrict__ bW2, const float* __restrict__ bb2,
    float* __restrict__ out,
    const double* __restrict__ dws)
{
    const int l    = threadIdx.x;
    const int w    = l >> 6;           // wave id 0..3
    const int lane = l & 63;
    const int bx   = blockIdx.x;
    const int by   = blockIdx.y;       // 0..4
    const int n0   = by * 4;

    int n = n0 + w;
    if (n >= NJOINT) return;           // only by==4 waves 1..3; no barriers on this path
    n = __builtin_amdgcn_readfirstlane(n);

    const int b = bx * 64 + lane;
    const int p = b * NJOINT + n;

    const float2 xv = *reinterpret_cast<const float2*>(pred_pts + 2 * p);

    float r[15];
    int kj;
    compute_point<USE_WS>(n, xv.x, xv.y,
                          kW1, kb1, kW2, kb2, wW1, wb1, wW2, wb2,
                          bW1, bb1, bW2, bb2, dws, r, kj);

    if (by == 4) {
        // n==16 remainder: direct stores (wave 0 only), no barriers on this path.
        float* o = out + (size_t)p * 15;
        #pragma unroll
        for (int i = 0; i < 15; ++i) o[i] = r[i];
        out[KJS_OFF + p] = (float)(kj + 1);
        float* mk = out + MASK_OFF + (size_t)p * 3;
        mk[0] = 1.0f;
        mk[1] = (kj >= 1) ? 1.0f : 0.0f;
        mk[2] = (kj >= 2) ? 1.0f : 0.0f;
        return;
    }

    // ---- stage tile in LDS: slot = w*64+lane, stride 17 dwords ----
    __shared__ float s_out[256 * 17];          // 17408 B
    {
        float* so = s_out + (w * 64 + lane) * 17;
        #pragma unroll
        for (int j = 0; j < 15; ++j) so[j] = r[j];
        so[15] = (float)(kj + 1);
    }
    __syncthreads();

    // ---- coalesced write-back: 16 rounds, lanes 0..239 ----
    // chunk = 60 contiguous dwords of out for (b = bx*64 + c, n = n0..n0+3).
    if (l < 240) {
        const int c_off = l / 60;              // 0..3
        const int jj    = l - c_off * 60;      // 0..59
        const int nl    = jj / 15;             // 0..3
        const int j     = jj - nl * 15;        // 0..14
        const int lbase = nl * 1088 + c_off * 17 + j;   // (nl*64+c_off)*17 + j
        size_t g = (size_t)((bx * 64 + c_off) * NJOINT + n0) * 15 + jj;
        #pragma unroll
        for (int rr = 0; rr < 16; ++rr) {
            out[g] = s_out[lbase + 68 * rr];   // +68 dwords per +4 chunks
            g += 1020;                          // 4 * 17 * 15 dwords
        }
    }

    // ---- k_js + mask from staged kj, per-b contiguous groups ----
    {
        const int bl  = l >> 2;                // 0..63
        const int nlr = l & 3;                 // 0..3
        const float kjf = s_out[(nlr * 64 + bl) * 17 + 15];
        const int pg = (bx * 64 + bl) * NJOINT + n0 + nlr;
        out[KJS_OFF + pg] = kjf;
        float* mk = out + MASK_OFF + (size_t)pg * 3;
        mk[0] = 1.0f;
        mk[1] = (kjf >= 1.5f) ? 1.0f : 0.0f;
        mk[2] = (kjf >= 2.5f) ? 1.0f : 0.0f;
    }
}

extern "C" void kernel_launch(void* const* d_in, const int* in_sizes, int n_in,
                              void* d_out, int out_size, void* d_ws, size_t ws_size,
                              hipStream_t stream) {
    (void)in_sizes; (void)n_in; (void)out_size;
    const bool use_ws = (d_ws != nullptr) && (ws_size >= (size_t)WS_DOUBLES * sizeof(double));
    dim3 grid(NBATCH / 64, 5);
    if (use_ws) {
        cvt_weights_f64<<<NJOINT, 256, 0, stream>>>(
            (const float*)d_in[1], (const float*)d_in[2],
            (const float*)d_in[3], (const float*)d_in[4],
            (const float*)d_in[5], (const float*)d_in[6],
            (const float*)d_in[7], (const float*)d_in[8],
            (double*)d_ws);
        mdn_fused<true><<<grid, 256, 0, stream>>>(
            (const float*)d_in[0],
            (const float*)d_in[1], (const float*)d_in[2],
            (const float*)d_in[3], (const float*)d_in[4],
            (const float*)d_in[5], (const float*)d_in[6],
            (const float*)d_in[7], (const float*)d_in[8],
            (const float*)d_in[9], (const float*)d_in[10],
            (const float*)d_in[11], (const float*)d_in[12],
            (float*)d_out, (const double*)d_ws);
    } else {
        mdn_fused<false><<<grid, 256, 0, stream>>>(
            (const float*)d_in[0],
            (const float*)d_in[1], (const float*)d_in[2],
            (const float*)d_in[3], (const float*)d_in[4],
            (const float*)d_in[5], (const float*)d_in[6],
            (const float*)d_in[7], (const float*)d_in[8],
            (const float*)d_in[9], (const float*)d_in[10],
            (const float*)d_in[11], (const float*)d_in[12],
            (float*)d_out, nullptr);
    }
}

// Round 6
// 142.392 us; speedup vs baseline: 2.2247x; 2.2247x over previous
//
#include <hip/hip_runtime.h>
#include <cmath>

// Problem constants: B=32768, N=17, D=2, K=3, H=64
#define NBATCH 32768
#define NJOINT 17
#define OUT0_ELEMS (NBATCH * NJOINT * 15)          // out[B,N,3,5]
#define KJS_OFF    OUT0_ELEMS                      // k_js[B,N]
#define MASK_OFF   (KJS_OFF + NBATCH * NJOINT)     // mask[B,N,3]

// fp64 weight workspace layout (per joint n, stride 774 doubles):
//  [0,128)   kW1  ([2][64]: row0=+0, row1=+64)
//  [128,192) kb1
//  [192,384) kW2  ([64][3])
//  [384,387) kb2
//  +387      same for the w-MLP
#define WN_STRIDE 774
#define WS_DOUBLES (NJOINT * WN_STRIDE)

__device__ __forceinline__ float sel3f(int i, float a, float b, float c) {
    return (i == 0) ? a : ((i == 1) ? b : c);
}

// --------------------------------------------------------------------------
// Prelude: convert k/w weights to fp64 once per launch.
// --------------------------------------------------------------------------
__global__ void cvt_weights_f64(
    const float* __restrict__ kW1, const float* __restrict__ kb1,
    const float* __restrict__ kW2, const float* __restrict__ kb2,
    const float* __restrict__ wW1, const float* __restrict__ wb1,
    const float* __restrict__ wW2, const float* __restrict__ wb2,
    double* __restrict__ dws)
{
    const int n = blockIdx.x;
    double* o = dws + (size_t)n * WN_STRIDE;
    for (int i = threadIdx.x; i < WN_STRIDE; i += blockDim.x) {
        int j = i;
        const float* W1 = kW1; const float* b1 = kb1;
        const float* W2 = kW2; const float* b2 = kb2;
        if (j >= 387) { j -= 387; W1 = wW1; b1 = wb1; W2 = wW2; b2 = wb2; }
        float v;
        if (j < 128)      v = W1[n * 128 + j];
        else if (j < 192) v = b1[n * 64 + (j - 128)];
        else if (j < 384) v = W2[n * 192 + (j - 192)];
        else              v = b2[n * 3 + (j - 384)];
        o[i] = (double)v;
    }
}

// --------------------------------------------------------------------------
// fp64 MLP (2 -> 64 -> 3) for TWO points sharing one weight stream.
// Per-point fma sequence is bit-identical to the passing kernels.
// --------------------------------------------------------------------------
__device__ __forceinline__ void mlp64_ws_2(
    const double* __restrict__ gws,
    double xA0, double xA1, double xB0, double xB1,
    double& lA0, double& lA1, double& lA2,
    double& lB0, double& lB1, double& lB2)
{
    const double* W1a = gws;
    const double* W1b = gws + 64;
    const double* b1  = gws + 128;
    const double* W2  = gws + 192;
    lA0 = gws[384]; lA1 = gws[385]; lA2 = gws[386];
    lB0 = gws[384]; lB1 = gws[385]; lB2 = gws[386];
    #pragma unroll 4
    for (int h = 0; h < 64; ++h) {
        const double wa = W1a[h], wb = W1b[h], bb = b1[h];
        const double w0 = W2[h * 3 + 0], w1 = W2[h * 3 + 1], w2 = W2[h * 3 + 2];
        double hvA = fmax(fma(xA1, wb, fma(xA0, wa, bb)), 0.0);
        double hvB = fmax(fma(xB1, wb, fma(xB0, wa, bb)), 0.0);
        lA0 = fma(hvA, w0, lA0); lB0 = fma(hvB, w0, lB0);
        lA1 = fma(hvA, w1, lA1); lB1 = fma(hvB, w1, lB1);
        lA2 = fma(hvA, w2, lA2); lB2 = fma(hvB, w2, lB2);
    }
}

// fallback: fp32 arrays, cvt in loop, both points (bit-identical per point)
__device__ __forceinline__ void mlp64_cvt_2(
    const float* __restrict__ W1, const float* __restrict__ b1f,
    const float* __restrict__ W2f, const float* __restrict__ b2f, int n,
    double xA0, double xA1, double xB0, double xB1,
    double& lA0, double& lA1, double& lA2,
    double& lB0, double& lB1, double& lB2)
{
    const float* W1a = W1 + n * 128;
    const float* W1b = W1a + 64;
    const float* b1  = b1f + n * 64;
    const float* W2  = W2f + n * 192;
    lA0 = (double)b2f[n * 3 + 0]; lB0 = lA0;
    lA1 = (double)b2f[n * 3 + 1]; lB1 = lA1;
    lA2 = (double)b2f[n * 3 + 2]; lB2 = lA2;
    #pragma unroll 4
    for (int h = 0; h < 64; ++h) {
        const double wa = (double)W1a[h], wb = (double)W1b[h], bb = (double)b1[h];
        const double w0 = (double)W2[h * 3 + 0], w1 = (double)W2[h * 3 + 1],
                     w2 = (double)W2[h * 3 + 2];
        double hvA = fmax(fma(xA1, wb, fma(xA0, wa, bb)), 0.0);
        double hvB = fmax(fma(xB1, wb, fma(xB0, wa, bb)), 0.0);
        lA0 = fma(hvA, w0, lA0); lB0 = fma(hvB, w0, lB0);
        lA1 = fma(hvA, w1, lA1); lB1 = fma(hvB, w1, lB1);
        lA2 = fma(hvA, w2, lA2); lB2 = fma(hvB, w2, lB2);
    }
}

// decisions + softmax from logits (identical scalar code to passing kernels)
__device__ __forceinline__ void decide(
    double kl0, double kl1, double kl2,
    double wl0, double wl1, double wl2,
    int& kj, int& i0, int& i1, int& i2,
    float& p0, float& p1, float& p2)
{
    kj = 0;
    {
        double m = kl0;
        if (kl1 > m) { m = kl1; kj = 1; }
        if (kl2 > m) { kj = 2; }
    }
    i0 = 0;
    {
        double m = wl0;
        if (wl1 > m) { m = wl1; i0 = 1; }
        if (wl2 > m) { i0 = 2; }
    }
    const int ia = (i0 == 0) ? 1 : 0;
    const int ib = (i0 == 2) ? 1 : 2;
    const double wa = ia ? wl1 : wl0;
    const double wb = (ib == 1) ? wl1 : wl2;
    i1 = (wb > wa) ? ib : ia;
    i2 = (wb > wa) ? ia : ib;

    const double mw = fmax(fmax(wl0, wl1), wl2);
    const float e0 = __expf((float)(wl0 - mw));
    const float e1 = __expf((float)(wl1 - mw));
    const float e2 = __expf((float)(wl2 - mw));
    const float inv = 1.0f / (e0 + e1 + e2);
    p0 = e0 * inv; p1 = e1 * inv; p2 = e2 * inv;
}

__device__ __forceinline__ void epilogue(
    const float acc[12], int i0, int i1, int i2,
    float p0, float p1, float p2, float r[15])
{
    r[0]  = p0; r[5] = p1; r[10] = p2;
    r[1]  = sel3f(i0, acc[0], acc[4], acc[8]);
    r[2]  = sel3f(i0, acc[1], acc[5], acc[9]);
    r[3]  = __expf(sel3f(i0, acc[2], acc[6], acc[10]));
    r[4]  = __expf(sel3f(i0, acc[3], acc[7], acc[11]));
    r[6]  = sel3f(i1, acc[0], acc[4], acc[8]);
    r[7]  = sel3f(i1, acc[1], acc[5], acc[9]);
    r[8]  = __expf(sel3f(i1, acc[2], acc[6], acc[10]));
    r[9]  = __expf(sel3f(i1, acc[3], acc[7], acc[11]));
    r[11] = sel3f(i2, acc[0], acc[4], acc[8]);
    r[12] = sel3f(i2, acc[1], acc[5], acc[9]);
    r[13] = __expf(sel3f(i2, acc[2], acc[6], acc[10]));
    r[14] = __expf(sel3f(i2, acc[3], acc[7], acc[11]));
}

// --------------------------------------------------------------------------
// Two points per lane through one s_load weight stream (proven r4 compute:
// 2x compute per SMEM-latency exposure -> ~2x per-wave issue duty).
// --------------------------------------------------------------------------
template<bool USE_WS>
__device__ __forceinline__ void compute2(
    int n, float xA0f, float xA1f, float xB0f, float xB1f,
    const float* __restrict__ kW1, const float* __restrict__ kb1,
    const float* __restrict__ kW2, const float* __restrict__ kb2,
    const float* __restrict__ wW1, const float* __restrict__ wb1,
    const float* __restrict__ wW2, const float* __restrict__ wb2,
    const float* __restrict__ bW1, const float* __restrict__ bb1,
    const float* __restrict__ bW2, const float* __restrict__ bb2,
    const double* __restrict__ dws,
    float rA[15], float rB[15], int& kjA, int& kjB)
{
    const double xA0 = (double)xA0f, xA1 = (double)xA1f;
    const double xB0 = (double)xB0f, xB1 = (double)xB1f;

    double klA0, klA1, klA2, klB0, klB1, klB2;
    double wlA0, wlA1, wlA2, wlB0, wlB1, wlB2;
    if constexpr (USE_WS) {
        const double* Wn = dws + (size_t)n * WN_STRIDE;
        mlp64_ws_2(Wn,       xA0, xA1, xB0, xB1, klA0, klA1, klA2, klB0, klB1, klB2);
        mlp64_ws_2(Wn + 387, xA0, xA1, xB0, xB1, wlA0, wlA1, wlA2, wlB0, wlB1, wlB2);
    } else {
        mlp64_cvt_2(kW1, kb1, kW2, kb2, n, xA0, xA1, xB0, xB1,
                    klA0, klA1, klA2, klB0, klB1, klB2);
        mlp64_cvt_2(wW1, wb1, wW2, wb2, n, xA0, xA1, xB0, xB1,
                    wlA0, wlA1, wlA2, wlB0, wlB1, wlB2);
    }

    // collapse fp64 state to small decision state before the bMLP
    int i0A, i1A, i2A, i0B, i1B, i2B;
    float p0A, p1A, p2A, p0B, p1B, p2B;
    decide(klA0, klA1, klA2, wlA0, wlA1, wlA2, kjA, i0A, i1A, i2A, p0A, p1A, p2A);
    decide(klB0, klB1, klB2, wlB0, wlB1, wlB2, kjB, i0B, i1B, i2B, p0B, p1B, p2B);

    // bMLP (fp32): 2 -> 128 -> 12, shared weight stream, two points
    float accA[12], accB[12];
    {
        const float* W1a = bW1 + n * 256;
        const float* W1b = W1a + 128;
        const float* b1  = bb1 + n * 128;
        const float* W2  = bW2 + n * 1536;
        const float* b2  = bb2 + n * 12;
        #pragma unroll
        for (int j = 0; j < 12; ++j) { accA[j] = b2[j]; accB[j] = b2[j]; }
        #pragma unroll 4
        for (int h = 0; h < 128; ++h) {
            const float wa = W1a[h], wb = W1b[h], bb = b1[h];
            float hvA = fmaxf(fmaf(xA1f, wb, fmaf(xA0f, wa, bb)), 0.0f);
            float hvB = fmaxf(fmaf(xB1f, wb, fmaf(xB0f, wa, bb)), 0.0f);
            #pragma unroll
            for (int j = 0; j < 12; ++j) {
                const float wv = W2[h * 12 + j];
                accA[j] = fmaf(hvA, wv, accA[j]);
                accB[j] = fmaf(hvB, wv, accB[j]);
            }
        }
    }

    epilogue(accA, i0A, i1A, i2A, p0A, p1A, p2A, rA);
    epilogue(accB, i0B, i1B, i2B, p0B, p1B, p2B, rB);
}

// --------------------------------------------------------------------------
// Block = 2 waves (128 threads) = 2 n x 128 b tile, 2 pts/lane.
// Wave w -> n = 2*by + w (wave-uniform); lane handles b = bx*128 + lane
// and b+64. vs r4: same compute, but LDS halves to 17408B (9 blocks/CU
// resident) and grid grows to 2304 blocks (9/CU) -> restores wave supply
// at r4's doubled per-wave duty.
// --------------------------------------------------------------------------
template<bool USE_WS>
__global__ __launch_bounds__(128, 4) void mdn_fused(
    const float* __restrict__ pred_pts,
    const float* __restrict__ kW1, const float* __restrict__ kb1,
    const float* __restrict__ kW2, const float* __restrict__ kb2,
    const float* __restrict__ wW1, const float* __restrict__ wb1,
    const float* __restrict__ wW2, const float* __restrict__ wb2,
    const float* __restrict__ bW1, const float* __restrict__ bb1,
    const float* __restrict__ bW2, const float* __restrict__ bb2,
    float* __restrict__ out,
    const double* __restrict__ dws)
{
    const int l    = threadIdx.x;
    const int w    = l >> 6;           // wave id 0..1
    const int lane = l & 63;
    const int bx   = blockIdx.x;       // 0..255
    const int by   = blockIdx.y;       // 0..8
    const int n0   = by * 2;

    if (by == 8 && w == 1) return;     // before any barrier; wave 0 never barriers on by==8
    int n = n0 + w;                    // by==8: w==0 -> n=16
    n = __builtin_amdgcn_readfirstlane(n);

    const int bA = bx * 128 + lane;
    const int bB = bA + 64;
    const int pA = bA * NJOINT + n;
    const int pB = bB * NJOINT + n;

    const float2 xA = *reinterpret_cast<const float2*>(pred_pts + 2 * pA);
    const float2 xB = *reinterpret_cast<const float2*>(pred_pts + 2 * pB);

    float rA[15], rB[15];
    int kjA, kjB;
    compute2<USE_WS>(n, xA.x, xA.y, xB.x, xB.y,
                     kW1, kb1, kW2, kb2, wW1, wb1, wW2, wb2,
                     bW1, bb1, bW2, bb2, dws, rA, rB, kjA, kjB);

    if (by == 8) {
        // n==16 remainder (1/17 of points): direct stores, no barriers.
        float* oA = out + (size_t)pA * 15;
        float* oB = out + (size_t)pB * 15;
        #pragma unroll
        for (int i = 0; i < 15; ++i) { oA[i] = rA[i]; oB[i] = rB[i]; }
        out[KJS_OFF + pA] = (float)(kjA + 1);
        out[KJS_OFF + pB] = (float)(kjB + 1);
        float* mkA = out + MASK_OFF + (size_t)pA * 3;
        mkA[0] = 1.0f; mkA[1] = (kjA >= 1) ? 1.0f : 0.0f; mkA[2] = (kjA >= 2) ? 1.0f : 0.0f;
        float* mkB = out + MASK_OFF + (size_t)pB * 3;
        mkB[0] = 1.0f; mkB[1] = (kjB >= 1) ? 1.0f : 0.0f; mkB[2] = (kjB >= 2) ? 1.0f : 0.0f;
        return;
    }

    // ---- stage tile in LDS: slot = w*128 + local_b, stride 17 dwords ----
    __shared__ float s_out[256 * 17];  // 17408 B -> 9 blocks/CU (LDS-capped)
    {
        float* soA = s_out + (w * 128 + lane) * 17;
        float* soB = soA + 64 * 17;
        #pragma unroll
        for (int j = 0; j < 15; ++j) { soA[j] = rA[j]; soB[j] = rB[j]; }
        soA[15] = (float)(kjA + 1);
        soB[15] = (float)(kjB + 1);
    }
    __syncthreads();

    // ---- coalesced write-back: 32 rounds, lanes 0..119 ----
    // chunk = 30 contiguous dwords of out for (b = bx*128 + b_local, n0..n0+1)
    if (l < 120) {
        const int c_off = l / 30;              // 0..3
        const int jj    = l - c_off * 30;      // 0..29
        const int nl    = jj / 15;             // 0..1
        const int j     = jj - nl * 15;        // 0..14
        const int lbase = (nl * 128 + c_off) * 17 + j;
        size_t g = (size_t)((bx * 128 + c_off) * NJOINT + n0) * 15 + jj;
        #pragma unroll
        for (int rr = 0; rr < 32; ++rr) {
            out[g] = s_out[lbase + 68 * rr];   // b_local += 4 -> +4*17 dwords
            g += 1020;                          // 4 * 17 * 15 dwords
        }
    }

    // ---- k_js + mask from staged kj, per-b contiguous pairs ----
    #pragma unroll
    for (int it = 0; it < 2; ++it) {
        const int q   = it * 128 + l;          // 0..255
        const int bl  = q >> 1;                // 0..127
        const int nlr = q & 1;                 // 0..1
        const float kjf = s_out[(nlr * 128 + bl) * 17 + 15];
        const int pg = (bx * 128 + bl) * NJOINT + n0 + nlr;
        out[KJS_OFF + pg] = kjf;
        float* mk = out + MASK_OFF + (size_t)pg * 3;
        mk[0] = 1.0f;
        mk[1] = (kjf >= 1.5f) ? 1.0f : 0.0f;
        mk[2] = (kjf >= 2.5f) ? 1.0f : 0.0f;
    }
}

extern "C" void kernel_launch(void* const* d_in, const int* in_sizes, int n_in,
                              void* d_out, int out_size, void* d_ws, size_t ws_size,
                              hipStream_t stream) {
    (void)in_sizes; (void)n_in; (void)out_size;
    const bool use_ws = (d_ws != nullptr) && (ws_size >= (size_t)WS_DOUBLES * sizeof(double));
    dim3 grid(NBATCH / 128, 9);
    if (use_ws) {
        cvt_weights_f64<<<NJOINT, 256, 0, stream>>>(
            (const float*)d_in[1], (const float*)d_in[2],
            (const float*)d_in[3], (const float*)d_in[4],
            (const float*)d_in[5], (const float*)d_in[6],
            (const float*)d_in[7], (const float*)d_in[8],
            (double*)d_ws);
        mdn_fused<true><<<grid, 128, 0, stream>>>(
            (const float*)d_in[0],
            (const float*)d_in[1], (const float*)d_in[2],
            (const float*)d_in[3], (const float*)d_in[4],
            (const float*)d_in[5], (const float*)d_in[6],
            (const float*)d_in[7], (const float*)d_in[8],
            (const float*)d_in[9], (const float*)d_in[10],
            (const float*)d_in[11], (const float*)d_in[12],
            (float*)d_out, (const double*)d_ws);
    } else {
        mdn_fused<false><<<grid, 128, 0, stream>>>(
            (const float*)d_in[0],
            (const float*)d_in[1], (const float*)d_in[2],
            (const float*)d_in[3], (const float*)d_in[4],
            (const float*)d_in[5], (const float*)d_in[6],
            (const float*)d_in[7], (const float*)d_in[8],
            (const float*)d_in[9], (const float*)d_in[10],
            (const float*)d_in[11], (const float*)d_in[12],
            (float*)d_out, nullptr);
    }
}